// Round 3
// baseline (186.338 us; speedup 1.0000x reference)
//
#include <hip/hip_runtime.h>
#include <math.h>

typedef __attribute__((ext_vector_type(8))) short bf16x8;
typedef __attribute__((ext_vector_type(16))) short bf16x16;
typedef __attribute__((ext_vector_type(4))) float f32x4;

#define NPIX 4096
#define C_DIM 128
#define SCALE 0.08838834764831845f   // 1/sqrt(128)

// workspace layout (bytes): bf16 hi/lo panels, [b][row][c] 2B elements, row-linear (no swizzle)
#define WS_XHI ((size_t)0)           // X: [b][q][c], scale folded in
#define WS_XLO ((size_t)4 << 20)
#define WS_YHI ((size_t)8 << 20)     // Y: [b][k][c]
#define WS_YLO ((size_t)12 << 20)
#define WS_NEED ((size_t)16 << 20)

static __device__ __forceinline__ short bf16_rne(float v) {
    unsigned int u = __float_as_uint(v);
    return (short)((u + 0x7fffu + ((u >> 16) & 1u)) >> 16);
}

// ---------------- pre-kernel: transpose [c][k] -> [k][c], fp32 -> bf16 hi+lo ----------------
// Tile 64c x 64k. Transpose on LDS *write* so both LDS phases are <=2-way (free) and
// global writes are fully coalesced 32B/lane runs.
__global__ __launch_bounds__(256) void conv_kernel(const float* __restrict__ x,
                                                   const float* __restrict__ y,
                                                   char* __restrict__ ws)
{
    __shared__ float T[64][65];      // [k][c], +1 pad: bank = (k + c) % 32
    int id = blockIdx.x;
    const int isY = (id >= 512);
    id &= 511;
    const int b  = id >> 7;
    const int c0 = ((id >> 6) & 1) * 64;
    const int k0 = (id & 63) * 64;
    const float* src = (isY ? y : x) + ((size_t)b * C_DIM + c0) * NPIX + k0;
    const int t = threadIdx.x;
    const float sc = isY ? 1.0f : SCALE;

    // read 64(c) x 64(k), coalesced along k; scatter into [k][c]
    {
        const int kl = (t & 15) * 4;
        #pragma unroll
        for (int i = 0; i < 4; ++i) {
            const int c = (t >> 4) + i * 16;
            const float4 v = *(const float4*)(src + (size_t)c * NPIX + kl);
            T[kl + 0][c] = v.x * sc;
            T[kl + 1][c] = v.y * sc;
            T[kl + 2][c] = v.z * sc;
            T[kl + 3][c] = v.w * sc;
        }
    }
    __syncthreads();

    char* dhi = ws + (isY ? WS_YHI : WS_XHI) + (size_t)b * (NPIX * 256);
    char* dlo = ws + (isY ? WS_YLO : WS_XLO) + (size_t)b * (NPIX * 256);

    const int k  = t >> 2;           // 0..63
    const int cq = t & 3;            // 16-channel group
    short hi[16], lo[16];
    #pragma unroll
    for (int u = 0; u < 16; ++u) {
        const float v = T[k][cq * 16 + u];
        const short h = bf16_rne(v);
        const float hv = __uint_as_float(((unsigned int)(unsigned short)h) << 16);
        hi[u] = h;
        lo[u] = bf16_rne(v - hv);    // exact residual in fp32
    }
    const size_t off = (size_t)(k0 + k) * 256 + (size_t)(c0 * 2) + (size_t)(cq * 32);
    *(bf16x16*)(dhi + off) = *(bf16x16*)hi;
    *(bf16x16*)(dlo + off) = *(bf16x16*)lo;
}

// ---------------- main kernel: direct-L2 B-fragments, no LDS staging, no K-loop barriers ----------------
__global__ __launch_bounds__(256, 2) void uv_mfma_kernel(const char* __restrict__ ws,
                                                         float* __restrict__ out)
{
    __shared__ float red[4][32][3];

    const int t    = threadIdx.x;
    const int w    = t >> 6;
    const int l    = t & 63;
    const int n16  = l & 15;
    const int quad = l >> 4;

    const int wg  = blockIdx.x;
    const int xcd = wg & 7;
    const int idx = wg >> 3;
    const int b   = xcd >> 1;                   // 2 XCDs per batch: hi+lo panels (2MB) fit 4MB L2
    const int qtile = ((xcd & 1) << 6) | idx;
    const int q0  = qtile * 32;

    const char* Xhi = ws + WS_XHI + (size_t)b * (NPIX * 256);
    const char* Xlo = ws + WS_XLO + (size_t)b * (NPIX * 256);

    // A-fragments (X, scale folded) in registers for the whole kernel.
    bf16x8 ah[2][4], al[2][4];
    #pragma unroll
    for (int qg = 0; qg < 2; ++qg) {
        const size_t rowoff = (size_t)(q0 + qg * 16 + n16) * 256 + (size_t)(quad * 16);
        #pragma unroll
        for (int c = 0; c < 4; ++c) {
            ah[qg][c] = *(const bf16x8*)(Xhi + rowoff + c * 64);
            al[qg][c] = *(const bf16x8*)(Xlo + rowoff + c * 64);
        }
    }

    // per-lane B pointers: this wave's 32 keys of each 128-key tile (2 groups of 16)
    const size_t lane_off = (size_t)(w * 32 + n16) * 256 + (size_t)(quad * 16);
    const char* ph0 = ws + WS_YHI + (size_t)b * (NPIX * 256) + lane_off;
    const char* ph1 = ph0 + 16 * 256;
    const char* pl0 = ws + WS_YLO + (size_t)b * (NPIX * 256) + lane_off;
    const char* pl1 = pl0 + 16 * 256;

    float gx[2];
    gx[0] = (float)((w * 32 + n16) & 63) + 0.5f;
    gx[1] = (float)((w * 32 + 16 + n16) & 63) + 0.5f;
    const float gyw = (float)(w >> 1) + 0.5f;

    float den[8], nu[8], nv[8];
    #pragma unroll
    for (int i = 0; i < 8; ++i) { den[i] = 0.f; nu[i] = 0.f; nv[i] = 0.f; }

    // BH double-buffered across k-tiles; BL single-buffered (issued at top of body,
    // consumed after the 16 ah*bh MFMAs) to stay under 256 VGPR at 2 waves/SIMD.
    bf16x8 BH[2][2][4];
    #pragma unroll
    for (int c = 0; c < 4; ++c) {
        BH[0][0][c] = *(const bf16x8*)(ph0 + c * 64);
        BH[0][1][c] = *(const bf16x8*)(ph1 + c * 64);
    }

    #pragma unroll 2
    for (int kt = 0; kt < 32; ++kt) {
        const int cur = kt & 1, nxt = cur ^ 1;
        const size_t adv = (size_t)kt * 32768;

        // BL for current tile — in flight while ah*bh MFMAs run
        bf16x8 BL[2][4];
        #pragma unroll
        for (int c = 0; c < 4; ++c) {
            BL[0][c] = *(const bf16x8*)(pl0 + adv + c * 64);
            BL[1][c] = *(const bf16x8*)(pl1 + adv + c * 64);
        }
        // BH prefetch for next tile
        if (kt < 31) {
            const size_t adv2 = adv + 32768;
            #pragma unroll
            for (int c = 0; c < 4; ++c) {
                BH[nxt][0][c] = *(const bf16x8*)(ph0 + adv2 + c * 64);
                BH[nxt][1][c] = *(const bf16x8*)(ph1 + adv2 + c * 64);
            }
        }

        f32x4 acc[2][2];
        #pragma unroll
        for (int qg = 0; qg < 2; ++qg)
            #pragma unroll
            for (int kg = 0; kg < 2; ++kg)
                acc[qg][kg] = (f32x4){0.f, 0.f, 0.f, 0.f};

        // pass 1: hi*hi (only needs BH[cur], loaded last iteration)
        #pragma unroll
        for (int c = 0; c < 4; ++c)
            #pragma unroll
            for (int qg = 0; qg < 2; ++qg)
                #pragma unroll
                for (int kg = 0; kg < 2; ++kg)
                    acc[qg][kg] = __builtin_amdgcn_mfma_f32_16x16x32_bf16(ah[qg][c], BH[cur][kg][c], acc[qg][kg], 0, 0, 0);
        // pass 2: lo*hi
        #pragma unroll
        for (int c = 0; c < 4; ++c)
            #pragma unroll
            for (int qg = 0; qg < 2; ++qg)
                #pragma unroll
                for (int kg = 0; kg < 2; ++kg)
                    acc[qg][kg] = __builtin_amdgcn_mfma_f32_16x16x32_bf16(al[qg][c], BH[cur][kg][c], acc[qg][kg], 0, 0, 0);
        // pass 3: hi*lo (BL arrived by now)
        #pragma unroll
        for (int c = 0; c < 4; ++c)
            #pragma unroll
            for (int qg = 0; qg < 2; ++qg)
                #pragma unroll
                for (int kg = 0; kg < 2; ++kg)
                    acc[qg][kg] = __builtin_amdgcn_mfma_f32_16x16x32_bf16(ah[qg][c], BL[kg][c], acc[qg][kg], 0, 0, 0);

        // softmax accumulation, no max-subtraction (|s| <= ~6.5 -> exp safe in fp32)
        const float gy = 2.0f * (float)kt + gyw;
        #pragma unroll
        for (int qg = 0; qg < 2; ++qg)
            #pragma unroll
            for (int kg = 0; kg < 2; ++kg)
                #pragma unroll
                for (int r = 0; r < 4; ++r) {
                    const float p = __expf(acc[qg][kg][r]);
                    const int row = qg * 4 + r;
                    den[row] += p;
                    nu[row]  += p * gx[kg];
                    nv[row]  += p * gy;
                }
    }

    // reduce across the 16 key-lanes of each row group
    #pragma unroll
    for (int i = 0; i < 8; ++i) {
        #pragma unroll
        for (int mk = 8; mk >= 1; mk >>= 1) {
            den[i] += __shfl_xor(den[i], mk);
            nu[i]  += __shfl_xor(nu[i],  mk);
            nv[i]  += __shfl_xor(nv[i],  mk);
        }
    }
    if (n16 == 0) {
        #pragma unroll
        for (int qg = 0; qg < 2; ++qg)
            #pragma unroll
            for (int r = 0; r < 4; ++r) {
                const int row = qg * 16 + quad * 4 + r;
                red[w][row][0] = den[qg * 4 + r];
                red[w][row][1] = nu[qg * 4 + r];
                red[w][row][2] = nv[qg * 4 + r];
            }
    }
    __syncthreads();
    if (t < 32) {
        float d = 0.f, u = 0.f, v = 0.f;
        #pragma unroll
        for (int ww = 0; ww < 4; ++ww) {
            d += red[ww][t][0];
            u += red[ww][t][1];
            v += red[ww][t][2];
        }
        const float inv = 1.0f / d;
        const int q = q0 + t;
        *(float2*)(out + ((size_t)b * NPIX + q) * 2) =
            make_float2(u * inv * 0.03125f - 1.0f, v * inv * 0.03125f - 1.0f);
    }
}

// ---------------- fallback (fp32 vector kernel) if workspace too small ----------------
__global__ __launch_bounds__(256, 2) void uv_attn_kernel(
    const float* __restrict__ x, const float* __restrict__ y, float* __restrict__ out)
{
    __shared__ float Xs[C_DIM][32];
    __shared__ float Ysf[64][128];
    const int tid = threadIdx.x;
    const int wgid = blockIdx.x;
    const int xcd = wgid & 7;
    const int jj_ = wgid >> 3;
    const int b = xcd & 3;
    const int qtile = ((xcd >> 2) << 6) | jj_;
    const int q0 = qtile * 32;
    const float* xb = x + (size_t)b * C_DIM * NPIX + q0;
    {
        const int cr = tid >> 3;
        const int cc = (tid & 7) << 2;
        #pragma unroll
        for (int i = 0; i < 4; ++i) {
            float4 v = *(const float4*)(xb + (size_t)(cr + (i << 5)) * NPIX + cc);
            v.x *= SCALE; v.y *= SCALE; v.z *= SCALE; v.w *= SCALE;
            *(float4*)(&Xs[cr + (i << 5)][cc]) = v;
        }
    }
    const int rg = tid >> 4;
    const int lane16 = tid & 15;
    const int r0 = rg << 1;
    const int col0 = lane16 << 3;
    float gxv[8];
    #pragma unroll
    for (int j2 = 0; j2 < 8; ++j2) gxv[j2] = (float)((col0 & 63) + j2) + 0.5f;
    const float gyb = (float)(lane16 >> 3) + 0.5f;
    float m_run[2] = {-INFINITY, -INFINITY};
    float den[2] = {0.f, 0.f}, nu[2] = {0.f, 0.f}, nv[2] = {0.f, 0.f};
    const int yr = tid >> 5;
    const int yc = (tid & 31) << 2;
    const float* ybase = y + (size_t)b * C_DIM * NPIX;
    for (int kt = 0; kt < 32; ++kt) {
        float S[2][8];
        #pragma unroll
        for (int r = 0; r < 2; ++r)
            #pragma unroll
            for (int j2 = 0; j2 < 8; ++j2) S[r][j2] = 0.f;
        #pragma unroll
        for (int cb = 0; cb < 2; ++cb) {
            __syncthreads();
            const float* yt = ybase + (size_t)(cb << 6) * NPIX + kt * 128;
            #pragma unroll
            for (int i = 0; i < 8; ++i)
                *(float4*)(&Ysf[yr + (i << 3)][yc]) =
                    *(const float4*)(yt + (size_t)(yr + (i << 3)) * NPIX + yc);
            __syncthreads();
            const int cbase = cb << 6;
            #pragma unroll 16
            for (int c = 0; c < 64; ++c) {
                const float2 xa = *(const float2*)(&Xs[cbase + c][r0]);
                const float4 ya = *(const float4*)(&Ysf[c][col0]);
                const float4 yb4 = *(const float4*)(&Ysf[c][col0 + 4]);
                S[0][0] += xa.x * ya.x;  S[0][1] += xa.x * ya.y;
                S[0][2] += xa.x * ya.z;  S[0][3] += xa.x * ya.w;
                S[0][4] += xa.x * yb4.x; S[0][5] += xa.x * yb4.y;
                S[0][6] += xa.x * yb4.z; S[0][7] += xa.x * yb4.w;
                S[1][0] += xa.y * ya.x;  S[1][1] += xa.y * ya.y;
                S[1][2] += xa.y * ya.z;  S[1][3] += xa.y * ya.w;
                S[1][4] += xa.y * yb4.x; S[1][5] += xa.y * yb4.y;
                S[1][6] += xa.y * yb4.z; S[1][7] += xa.y * yb4.w;
            }
        }
        const float gy = gyb + 2.0f * (float)kt;
        #pragma unroll
        for (int r = 0; r < 2; ++r) {
            float tmax = S[r][0];
            #pragma unroll
            for (int j2 = 1; j2 < 8; ++j2) tmax = fmaxf(tmax, S[r][j2]);
            #pragma unroll
            for (int mk = 8; mk >= 1; mk >>= 1) tmax = fmaxf(tmax, __shfl_xor(tmax, mk, 16));
            const float mnew = fmaxf(m_run[r], tmax);
            const float alpha = __expf(m_run[r] - mnew);
            m_run[r] = mnew;
            float psum = 0.f, pu = 0.f;
            #pragma unroll
            for (int j2 = 0; j2 < 8; ++j2) {
                const float p = __expf(S[r][j2] - mnew);
                psum += p; pu += p * gxv[j2];
            }
            den[r] = den[r] * alpha + psum;
            nu[r] = nu[r] * alpha + pu;
            nv[r] = nv[r] * alpha + gy * psum;
        }
    }
    #pragma unroll
    for (int r = 0; r < 2; ++r)
        #pragma unroll
        for (int mk = 8; mk >= 1; mk >>= 1) {
            den[r] += __shfl_xor(den[r], mk, 16);
            nu[r] += __shfl_xor(nu[r], mk, 16);
            nv[r] += __shfl_xor(nv[r], mk, 16);
        }
    if (lane16 == 0) {
        #pragma unroll
        for (int r = 0; r < 2; ++r) {
            const float inv = 1.0f / den[r];
            const int q = q0 + r0 + r;
            *(float2*)(out + ((size_t)b * NPIX + q) * 2) =
                make_float2(nu[r] * inv * 0.03125f - 1.0f, nv[r] * inv * 0.03125f - 1.0f);
        }
    }
}

extern "C" void kernel_launch(void* const* d_in, const int* in_sizes, int n_in,
                              void* d_out, int out_size, void* d_ws, size_t ws_size,
                              hipStream_t stream) {
    const float* x = (const float*)d_in[0];
    const float* y = (const float*)d_in[1];
    float* out = (float*)d_out;
    if (ws_size >= WS_NEED) {
        hipLaunchKernelGGL(conv_kernel, dim3(1024), dim3(256), 0, stream, x, y, (char*)d_ws);
        hipLaunchKernelGGL(uv_mfma_kernel, dim3(512), dim3(256), 0, stream,
                           (const char*)d_ws, out);
    } else {
        hipLaunchKernelGGL(uv_attn_kernel, dim3(512), dim3(256), 0, stream, x, y, out);
    }
}

// Round 4
// 124.917 us; speedup vs baseline: 1.4917x; 1.4917x over previous
//
#include <hip/hip_runtime.h>
#include <math.h>

typedef __attribute__((ext_vector_type(8))) short bf16x8;
typedef __attribute__((ext_vector_type(4))) float f32x4;

#define NPIX 4096
#define C_DIM 128
#define SCALE 0.08838834764831845f   // 1/sqrt(128)

// workspace: Y panels only, bf16 hi/lo, [b][k][c] rows of 256B, granule-swizzled
#define WS_YHI ((size_t)0)
#define WS_YLO ((size_t)4 << 20)
#define WS_NEED ((size_t)8 << 20)

static __device__ __forceinline__ short bf16_rne(float v) {
    unsigned int u = __float_as_uint(v);
    return (short)((u + 0x7fffu + ((u >> 16) & 1u)) >> 16);
}

// ---------------- conv: Y only, [c][k] -> [k][c] bf16 hi+lo, XCD-matched ----------------
// block -> XCD map mirrors the main kernel (b = (blockIdx&7)>>1) so each batch's panel
// is written into, and later read from, the same XCD-pair's L2.
__global__ __launch_bounds__(256) void conv_y(const float* __restrict__ y,
                                              char* __restrict__ ws)
{
    __shared__ float T[64][65];          // [k][c], +1 pad
    const int id   = blockIdx.x;
    const int xcd  = id & 7;
    const int b    = xcd >> 1;
    const int tile = ((xcd & 1) << 6) | (id >> 3);   // 0..127
    const int c0   = (tile & 1) * 64;
    const int k0   = (tile >> 1) * 64;
    const float* src = y + ((size_t)b * C_DIM + c0) * NPIX + k0;
    const int t = threadIdx.x;

    // load 64c x 64k (all loads issued before any LDS write -> max MLP)
    float4 v[4];
    const int kl = (t & 15) * 4;
    #pragma unroll
    for (int i = 0; i < 4; ++i)
        v[i] = *(const float4*)(src + (size_t)((t >> 4) + i * 16) * NPIX + kl);
    #pragma unroll
    for (int i = 0; i < 4; ++i) {
        const int c = (t >> 4) + i * 16;
        T[kl + 0][c] = v[i].x;
        T[kl + 1][c] = v[i].y;
        T[kl + 2][c] = v[i].z;
        T[kl + 3][c] = v[i].w;
    }
    __syncthreads();

    char* dhi = ws + WS_YHI + (size_t)b * (NPIX * 256);
    char* dlo = ws + WS_YLO + (size_t)b * (NPIX * 256);
    const int k  = t >> 2;              // 0..63
    const int cq = t & 3;               // 16-channel group
    short hi[16], lo[16];
    #pragma unroll
    for (int u = 0; u < 16; ++u) {
        const float f = T[k][cq * 16 + u];
        const short h = bf16_rne(f);
        const float hv = __uint_as_float(((unsigned int)(unsigned short)h) << 16);
        hi[u] = h;
        lo[u] = bf16_rne(f - hv);       // exact residual in fp32
    }
    const int kk = k0 + k;
    #pragma unroll
    for (int gi = 0; gi < 2; ++gi) {
        const int g  = (c0 >> 3) + cq * 2 + gi;     // global 16B-granule index 0..15
        const int gs = g ^ (kk & 7);                // bank swizzle (within 8-granule half)
        const size_t off = (size_t)kk * 256 + (size_t)gs * 16;
        *(bf16x8*)(dhi + off) = *(bf16x8*)(hi + gi * 8);
        *(bf16x8*)(dlo + off) = *(bf16x8*)(lo + gi * 8);
    }
}

// ---------------- main: S^T MFMA, X in registers, true LDS double-buffer ----------------
// D[m=key][n=query]; A = Y (streamed, LDS dbuf), B = X (native gather -> regs, one-time).
__global__ __launch_bounds__(256, 1) void uv_mfma2(const char* __restrict__ ws,
                                                   const float* __restrict__ x,
                                                   float* __restrict__ out)
{
    __shared__ char Ys[2][32768];       // per buf: hi 16KB | lo 16KB (64 keys x 256B)

    const int t = threadIdx.x, w = t >> 6, l = t & 63;
    const int n16 = l & 15, quad = l >> 4;
    const int wg = blockIdx.x;
    const int xcd = wg & 7;
    const int b = xcd >> 1;                          // 2 XCDs per batch
    const int qtile = ((xcd & 1) << 5) | (wg >> 3);  // 0..63
    const int q0 = qtile * 64;

    // ---- one-time: gather X (native [c][q]) and convert to bf16 hi/lo B-fragments ----
    // B[k=quad*8+j][n=lane&15]: element j <-> channel c = cc*32 + quad*8 + j, n <-> query.
    const float* xb = x + (size_t)b * C_DIM * NPIX;
    bf16x8 bh[4][4], bl[4][4];          // [cc][qg] — 128 VGPRs, loop-invariant
    #pragma unroll
    for (int cc = 0; cc < 4; ++cc)
        #pragma unroll
        for (int qg = 0; qg < 4; ++qg) {
            short h8[8], l8[8];
            #pragma unroll
            for (int j = 0; j < 8; ++j) {
                const float f = xb[(size_t)(cc * 32 + quad * 8 + j) * NPIX
                                   + (q0 + qg * 16 + n16)] * SCALE;
                const short h = bf16_rne(f);
                const float hv = __uint_as_float(((unsigned int)(unsigned short)h) << 16);
                h8[j] = h;
                l8[j] = bf16_rne(f - hv);
            }
            bh[cc][qg] = *(bf16x8*)h8;
            bl[cc][qg] = *(bf16x8*)l8;
        }

    const char* Yhi = ws + WS_YHI + (size_t)b * (NPIX * 256);
    const char* Ylo = ws + WS_YLO + (size_t)b * (NPIX * 256);

    // A-read LDS offsets (swizzled), loop-invariant. A[m=key=lane&15][k=quad*8+j].
    const int keyl = (w << 4) | n16;    // this wave's key row 0..63 within tile
    int aoff[4];
    #pragma unroll
    for (int cc = 0; cc < 4; ++cc)
        aoff[cc] = keyl * 256 + (((cc * 4 + quad) ^ (keyl & 7)) << 4);

    // D rows of this lane: keys w*16 + quad*4 + r  ->  gx loop-invariant, gy = kt + 0.5
    float gxr[4];
    #pragma unroll
    for (int r = 0; r < 4; ++r) gxr[r] = (float)((w << 4) + quad * 4 + r) + 0.5f;

    // staging assignment: wave w copies 8KB: w<2 -> hi half, w>=2 -> lo half
    const char* gsrc = (w < 2) ? Yhi : Ylo;
    const int lds_half = ((w < 2) ? 0 : 16384) + (w & 1) * 8192;
    const int g_half = (w & 1) * 8192;

    float den[4], nu[4], nv[4];
    #pragma unroll
    for (int i = 0; i < 4; ++i) { den[i] = 0.f; nu[i] = 0.f; nv[i] = 0.f; }

    // preload tile 0 into buf 0
    #pragma unroll
    for (int i = 0; i < 8; ++i)
        __builtin_amdgcn_global_load_lds(
            (const __attribute__((address_space(1))) void*)(gsrc + g_half + i * 1024 + l * 16),
            (__attribute__((address_space(3))) void*)(&Ys[0][lds_half + i * 1024]), 16, 0, 0);

    for (int kt = 0; kt < 64; ++kt) {
        const int cur = kt & 1;
        __syncthreads();   // drains buf[cur] loads (issued last iter); all waves off buf[cur^1]

        if (kt < 63) {     // issue NEXT tile into the other buffer — lands during compute
            const char* gt = gsrc + (size_t)(kt + 1) * 16384 + g_half;
            #pragma unroll
            for (int i = 0; i < 8; ++i)
                __builtin_amdgcn_global_load_lds(
                    (const __attribute__((address_space(1))) void*)(gt + i * 1024 + l * 16),
                    (__attribute__((address_space(3))) void*)(&Ys[cur ^ 1][lds_half + i * 1024]),
                    16, 0, 0);
        }

        f32x4 acc[4];
        #pragma unroll
        for (int qg = 0; qg < 4; ++qg) acc[qg] = (f32x4){0.f, 0.f, 0.f, 0.f};

        #pragma unroll
        for (int cc = 0; cc < 4; ++cc) {
            const bf16x8 Ahi = *(const bf16x8*)(&Ys[cur][aoff[cc]]);
            const bf16x8 Alo = *(const bf16x8*)(&Ys[cur][16384 + aoff[cc]]);
            #pragma unroll
            for (int qg = 0; qg < 4; ++qg) {
                acc[qg] = __builtin_amdgcn_mfma_f32_16x16x32_bf16(Ahi, bh[cc][qg], acc[qg], 0, 0, 0);
                acc[qg] = __builtin_amdgcn_mfma_f32_16x16x32_bf16(Alo, bh[cc][qg], acc[qg], 0, 0, 0);
                acc[qg] = __builtin_amdgcn_mfma_f32_16x16x32_bf16(Ahi, bl[cc][qg], acc[qg], 0, 0, 0);
            }
        }

        // softmax accumulation, no max-subtraction (|s| <= ~7 -> exp safe in fp32)
        const float gyt = (float)kt + 0.5f;
        #pragma unroll
        for (int qg = 0; qg < 4; ++qg) {
            float psum = 0.f, pgx = 0.f;
            #pragma unroll
            for (int r = 0; r < 4; ++r) {
                const float p = __expf(acc[qg][r]);
                psum += p;
                pgx  += p * gxr[r];
            }
            den[qg] += psum;
            nu[qg]  += pgx;
            nv[qg]  += gyt * psum;
        }
    }

    // ---- reduce: across quads (same n16) then across waves via LDS ----
    #pragma unroll
    for (int qg = 0; qg < 4; ++qg) {
        #pragma unroll
        for (int mk = 16; mk <= 32; mk <<= 1) {
            den[qg] += __shfl_xor(den[qg], mk);
            nu[qg]  += __shfl_xor(nu[qg],  mk);
            nv[qg]  += __shfl_xor(nv[qg],  mk);
        }
    }
    __syncthreads();                    // everyone done with Ys — reuse buf0 as scratch
    float* red = (float*)&Ys[0][0];     // [4 waves][64 q][3]
    if (quad == 0) {
        #pragma unroll
        for (int qg = 0; qg < 4; ++qg) {
            const int qi = (w * 64 + qg * 16 + n16) * 3;
            red[qi + 0] = den[qg];
            red[qi + 1] = nu[qg];
            red[qi + 2] = nv[qg];
        }
    }
    __syncthreads();
    if (t < 64) {
        float d = 0.f, u = 0.f, v = 0.f;
        #pragma unroll
        for (int ww = 0; ww < 4; ++ww) {
            d += red[(ww * 64 + t) * 3 + 0];
            u += red[(ww * 64 + t) * 3 + 1];
            v += red[(ww * 64 + t) * 3 + 2];
        }
        const float inv = 1.0f / d;
        *(float2*)(out + ((size_t)b * NPIX + q0 + t) * 2) =
            make_float2(u * inv * 0.03125f - 1.0f, v * inv * 0.03125f - 1.0f);
    }
}

// ---------------- fallback (fp32 vector kernel, round-1, known-correct) ----------------
__global__ __launch_bounds__(256, 2) void uv_attn_kernel(
    const float* __restrict__ x, const float* __restrict__ y, float* __restrict__ out)
{
    __shared__ float Xs[C_DIM][32];
    __shared__ float Ysf[64][128];
    const int tid = threadIdx.x;
    const int wgid = blockIdx.x;
    const int xcd = wgid & 7;
    const int b = xcd & 3;
    const int q0 = (((xcd >> 2) << 6) | (wgid >> 3)) * 32;
    const float* xb = x + (size_t)b * C_DIM * NPIX + q0;
    {
        const int cr = tid >> 3;
        const int cc = (tid & 7) << 2;
        #pragma unroll
        for (int i = 0; i < 4; ++i) {
            float4 v = *(const float4*)(xb + (size_t)(cr + (i << 5)) * NPIX + cc);
            v.x *= SCALE; v.y *= SCALE; v.z *= SCALE; v.w *= SCALE;
            *(float4*)(&Xs[cr + (i << 5)][cc]) = v;
        }
    }
    const int rg = tid >> 4;
    const int lane16 = tid & 15;
    const int r0 = rg << 1;
    const int col0 = lane16 << 3;
    float gxv[8];
    #pragma unroll
    for (int j2 = 0; j2 < 8; ++j2) gxv[j2] = (float)((col0 & 63) + j2) + 0.5f;
    const float gyb = (float)(lane16 >> 3) + 0.5f;
    float m_run[2] = {-INFINITY, -INFINITY};
    float den[2] = {0.f, 0.f}, nu[2] = {0.f, 0.f}, nv[2] = {0.f, 0.f};
    const int yr = tid >> 5;
    const int yc = (tid & 31) << 2;
    const float* ybase = y + (size_t)b * C_DIM * NPIX;
    for (int kt = 0; kt < 32; ++kt) {
        float S[2][8];
        #pragma unroll
        for (int r = 0; r < 2; ++r)
            #pragma unroll
            for (int j2 = 0; j2 < 8; ++j2) S[r][j2] = 0.f;
        #pragma unroll
        for (int cb = 0; cb < 2; ++cb) {
            __syncthreads();
            const float* yt = ybase + (size_t)(cb << 6) * NPIX + kt * 128;
            #pragma unroll
            for (int i = 0; i < 8; ++i)
                *(float4*)(&Ysf[yr + (i << 3)][yc]) =
                    *(const float4*)(yt + (size_t)(yr + (i << 3)) * NPIX + yc);
            __syncthreads();
            const int cbase = cb << 6;
            #pragma unroll 16
            for (int c = 0; c < 64; ++c) {
                const float2 xa = *(const float2*)(&Xs[cbase + c][r0]);
                const float4 ya = *(const float4*)(&Ysf[c][col0]);
                const float4 yb4 = *(const float4*)(&Ysf[c][col0 + 4]);
                S[0][0] += xa.x * ya.x;  S[0][1] += xa.x * ya.y;
                S[0][2] += xa.x * ya.z;  S[0][3] += xa.x * ya.w;
                S[0][4] += xa.x * yb4.x; S[0][5] += xa.x * yb4.y;
                S[0][6] += xa.x * yb4.z; S[0][7] += xa.x * yb4.w;
                S[1][0] += xa.y * ya.x;  S[1][1] += xa.y * ya.y;
                S[1][2] += xa.y * ya.z;  S[1][3] += xa.y * ya.w;
                S[1][4] += xa.y * yb4.x; S[1][5] += xa.y * yb4.y;
                S[1][6] += xa.y * yb4.z; S[1][7] += xa.y * yb4.w;
            }
        }
        const float gy = gyb + 2.0f * (float)kt;
        #pragma unroll
        for (int r = 0; r < 2; ++r) {
            float tmax = S[r][0];
            #pragma unroll
            for (int j2 = 1; j2 < 8; ++j2) tmax = fmaxf(tmax, S[r][j2]);
            #pragma unroll
            for (int mk = 8; mk >= 1; mk >>= 1) tmax = fmaxf(tmax, __shfl_xor(tmax, mk, 16));
            const float mnew = fmaxf(m_run[r], tmax);
            const float alpha = __expf(m_run[r] - mnew);
            m_run[r] = mnew;
            float psum = 0.f, pu = 0.f;
            #pragma unroll
            for (int j2 = 0; j2 < 8; ++j2) {
                const float p = __expf(S[r][j2] - mnew);
                psum += p; pu += p * gxv[j2];
            }
            den[r] = den[r] * alpha + psum;
            nu[r] = nu[r] * alpha + pu;
            nv[r] = nv[r] * alpha + gy * psum;
        }
    }
    #pragma unroll
    for (int r = 0; r < 2; ++r)
        #pragma unroll
        for (int mk = 8; mk >= 1; mk >>= 1) {
            den[r] += __shfl_xor(den[r], mk, 16);
            nu[r] += __shfl_xor(nu[r], mk, 16);
            nv[r] += __shfl_xor(nv[r], mk, 16);
        }
    if (lane16 == 0) {
        #pragma unroll
        for (int r = 0; r < 2; ++r) {
            const float inv = 1.0f / den[r];
            const int q = q0 + r0 + r;
            *(float2*)(out + ((size_t)b * NPIX + q) * 2) =
                make_float2(nu[r] * inv * 0.03125f - 1.0f, nv[r] * inv * 0.03125f - 1.0f);
        }
    }
}

extern "C" void kernel_launch(void* const* d_in, const int* in_sizes, int n_in,
                              void* d_out, int out_size, void* d_ws, size_t ws_size,
                              hipStream_t stream) {
    const float* x = (const float*)d_in[0];
    const float* y = (const float*)d_in[1];
    float* out = (float*)d_out;
    if (ws_size >= WS_NEED) {
        hipLaunchKernelGGL(conv_y, dim3(512), dim3(256), 0, stream, y, (char*)d_ws);
        hipLaunchKernelGGL(uv_mfma2, dim3(256), dim3(256), 0, stream,
                           (const char*)d_ws, x, out);
    } else {
        hipLaunchKernelGGL(uv_attn_kernel, dim3(512), dim3(256), 0, stream, x, y, out);
    }
}